// Round 5
// baseline (4657.631 us; speedup 1.0000x reference)
//
#include <hip/hip_runtime.h>
#include <hip/hip_bf16.h>

#define NN 32768
#define NE 524288
#define FF 128

typedef unsigned int u32;
typedef unsigned short u16;

__device__ __forceinline__ u16 f2bf(float f) {
    u32 x = __builtin_bit_cast(u32, f);
    x += 0x7fffu + ((x >> 16) & 1u);
    return (u16)(x >> 16);
}
__device__ __forceinline__ float bflo(u32 u) {
    return __builtin_bit_cast(float, u << 16);
}
__device__ __forceinline__ float bfhi(u32 u) {
    return __builtin_bit_cast(float, u & 0xffff0000u);
}
// full reduction over each 16-lane row via DPP rotate-and-add (VALU pipe, no LDS)
__device__ __forceinline__ float red16(float v) {
    v += __builtin_bit_cast(float, __builtin_amdgcn_update_dpp(
        0, __builtin_bit_cast(int, v), 0x121, 0xF, 0xF, true)); // row_ror:1
    v += __builtin_bit_cast(float, __builtin_amdgcn_update_dpp(
        0, __builtin_bit_cast(int, v), 0x122, 0xF, 0xF, true)); // row_ror:2
    v += __builtin_bit_cast(float, __builtin_amdgcn_update_dpp(
        0, __builtin_bit_cast(int, v), 0x124, 0xF, 0xF, true)); // row_ror:4
    v += __builtin_bit_cast(float, __builtin_amdgcn_update_dpp(
        0, __builtin_bit_cast(int, v), 0x128, 0xF, 0xF, true)); // row_ror:8
    return v;
}
__device__ __forceinline__ float silu(float a) {
    return a / (1.f + __expf(-a));
}

// ---------------------------------------------------------------------------
// Node kernel: wave = head h (4 waves/block). W columns live in bf16-packed
// VGPRs (16 u32 x 5 matrices); x broadcast via ds_swizzle within 32-lane
// halves (lane half = node). Outputs stored bf16.
// NODE PAIRS STRIDE BY BLOCK (all 4 waves of a block cover the 4 heads of
// the same nodes) -- round-3 bugfix: wave-strided loop left 3/4 of columns
// unwritten (poison).
// ---------------------------------------------------------------------------
__global__ __launch_bounds__(256, 4) void node_kernel(
    const float* __restrict__ x,
    const float* __restrict__ Wq, const float* __restrict__ Wk,
    const float* __restrict__ Wv, const float* __restrict__ Wqe,
    const float* __restrict__ Wke,
    u16* __restrict__ QI, u16* __restrict__ KI, u16* __restrict__ VI,
    u16* __restrict__ QE, u16* __restrict__ KE)
{
    const int lane = threadIdx.x & 63;
    const int h    = threadIdx.x >> 6;          // wave index = head
    const int e    = lane & 31;
    const int wb   = h * 1024 + e;              // W[h, d, e] = [h*1024 + d*32 + e]

    u32 wq[16], wk[16], wv[16], wqe[16], wke[16];
#pragma unroll
    for (int dp = 0; dp < 16; ++dp) {
        const int i0 = wb + (2 * dp) * 32, i1 = wb + (2 * dp + 1) * 32;
        wq [dp] = (u32)f2bf(Wq [i0]) | ((u32)f2bf(Wq [i1]) << 16);
        wk [dp] = (u32)f2bf(Wk [i0]) | ((u32)f2bf(Wk [i1]) << 16);
        wv [dp] = (u32)f2bf(Wv [i0]) | ((u32)f2bf(Wv [i1]) << 16);
        wqe[dp] = (u32)f2bf(Wqe[i0]) | ((u32)f2bf(Wqe[i1]) << 16);
        wke[dp] = (u32)f2bf(Wke[i0]) | ((u32)f2bf(Wke[i1]) << 16);
    }

    for (int p = blockIdx.x; p < NN / 2; p += gridDim.x) {
        const int n = 2 * p + (lane >> 5);      // lanes 0-31: node 2p, 32-63: 2p+1
        const float xv = x[(size_t)n * FF + h * 32 + e];
        const int xi = __builtin_bit_cast(int, xv);
        float aq = 0.f, ak = 0.f, av = 0.f, aqe = 0.f, ake = 0.f;
        // ds_swizzle offset must be a parse-time literal -> macro-expanded steps
#define NODE_STEP(dp)                                                          \
        {                                                                      \
            const float x0 = __builtin_bit_cast(float,                         \
                __builtin_amdgcn_ds_swizzle(xi, ((2 * (dp)) << 5)));           \
            const float x1 = __builtin_bit_cast(float,                         \
                __builtin_amdgcn_ds_swizzle(xi, ((2 * (dp) + 1) << 5)));       \
            aq  += x0 * bflo(wq [(dp)]) + x1 * bfhi(wq [(dp)]);                \
            ak  += x0 * bflo(wk [(dp)]) + x1 * bfhi(wk [(dp)]);                \
            av  += x0 * bflo(wv [(dp)]) + x1 * bfhi(wv [(dp)]);                \
            aqe += x0 * bflo(wqe[(dp)]) + x1 * bfhi(wqe[(dp)]);                \
            ake += x0 * bflo(wke[(dp)]) + x1 * bfhi(wke[(dp)]);                \
        }
        NODE_STEP(0)  NODE_STEP(1)  NODE_STEP(2)  NODE_STEP(3)
        NODE_STEP(4)  NODE_STEP(5)  NODE_STEP(6)  NODE_STEP(7)
        NODE_STEP(8)  NODE_STEP(9)  NODE_STEP(10) NODE_STEP(11)
        NODE_STEP(12) NODE_STEP(13) NODE_STEP(14) NODE_STEP(15)
#undef NODE_STEP
        const size_t o = (size_t)n * FF + h * 32 + e;
        QI[o] = f2bf(silu(aq));
        KI[o] = f2bf(silu(ak));
        VI[o] = f2bf(av);
        QE[o] = f2bf(silu(aqe));
        KE[o] = f2bf(silu(ake));
    }
}

// ---------------------------------------------------------------------------
// Edge kernel. Per wave, batches of 16 edges:
//   A) rbf -> feat_s (b128 LDS writes)
//   B) lanes 0..15: invariants (float4 write) + sid/rid/cut kept in REGISTERS
//   C) feat[16,36] @ [WfInv|WfEv] : feat as b128 broadcasts (9/edge),
//      weights bf16-packed, one ds_read_b64 per j per lane
//   D) bf16 q/k/v gathers, DPP row-reduce, degree-row d_ev scatter, atomics
// ---------------------------------------------------------------------------
__global__ __launch_bounds__(256, 4) void edge_kernel(
    const float* __restrict__ ev_feat,   // [N,16]
    const float* __restrict__ rbf,       // [E,32]
    const float* __restrict__ sh,        // [E,16]
    const float* __restrict__ cutoffs,   // [E]
    const float* __restrict__ WfInv,     // [36,128]
    const float* __restrict__ bfInv,     // [128]
    const float* __restrict__ WfEv,      // [36,128]
    const float* __restrict__ bfEv,      // [128]
    const int* __restrict__ senders,
    const int* __restrict__ receivers,
    const u32* __restrict__ QIh, const u32* __restrict__ KIh,
    const u32* __restrict__ VIh, const u32* __restrict__ QEh,
    const u32* __restrict__ KEh,
    float* __restrict__ dinv,            // [N,128]
    float* __restrict__ devout)          // [N,16]
{
    __shared__ uint2 wcomb[36 * 64];     // [j][lane] -> {bf16x2 WfInv cols, WfEv cols}
    __shared__ float feat_s[4][16][40];  // row padded to 40 for aligned b128

    for (int i = threadIdx.x; i < 36 * 64; i += 256) {
        const int j = i >> 6, l = i & 63;
        uint2 w;
        w.x = (u32)f2bf(WfInv[j * 128 + 2 * l]) | ((u32)f2bf(WfInv[j * 128 + 2 * l + 1]) << 16);
        w.y = (u32)f2bf(WfEv [j * 128 + 2 * l]) | ((u32)f2bf(WfEv [j * 128 + 2 * l + 1]) << 16);
        wcomb[i] = w;
    }
    __syncthreads();

    const int wave = threadIdx.x >> 6;
    const int lane = threadIdx.x & 63;
    const float2 bi = *(const float2*)&bfInv[2 * lane];
    const float2 be = *(const float2*)&bfEv[2 * lane];
    const float rs32 = 0.17677669529663687f;   // 1/sqrt(32)

    const int nbatches = NE / 16;
    const int gw = blockIdx.x * 4 + wave;
    const int nw = gridDim.x * 4;

    for (int bi_ = gw; bi_ < nbatches; bi_ += nw) {
        const int ebase = bi_ * 16;

        // ---- phase A: rbf rows -> feat_s ----
        {
            const int b = lane >> 2, chunk = lane & 3;
            const float4* src = (const float4*)&rbf[(size_t)(ebase + b) * 32 + chunk * 8];
            float4* dst = (float4*)&feat_s[wave][b][chunk * 8];
            dst[0] = src[0];
            dst[1] = src[1];
        }
        // ---- phase B: invariants + edge scalars in regs (lanes 0..15) ----
        int sreg = 0, rreg = 0;
        float creg = 0.f;
        if (lane < 16) {
            const int e = ebase + lane;
            sreg = senders[e];
            rreg = receivers[e];
            creg = cutoffs[e];
            float es[16], er[16];
            const float4* es4 = (const float4*)(ev_feat + (size_t)sreg * 16);
            const float4* er4 = (const float4*)(ev_feat + (size_t)rreg * 16);
#pragma unroll
            for (int q = 0; q < 4; ++q) {
                const float4 a = es4[q], b4 = er4[q];
                es[4 * q] = a.x; es[4 * q + 1] = a.y; es[4 * q + 2] = a.z; es[4 * q + 3] = a.w;
                er[4 * q] = b4.x; er[4 * q + 1] = b4.y; er[4 * q + 2] = b4.z; er[4 * q + 3] = b4.w;
            }
            float d0 = es[0] - er[0];
            float i0 = d0 * d0, i1 = 0.f, i2 = 0.f, i3 = 0.f;
#pragma unroll
            for (int k = 1; k < 4; ++k) { float d = es[k] - er[k]; i1 += d * d; }
#pragma unroll
            for (int k = 4; k < 9; ++k) { float d = es[k] - er[k]; i2 += d * d; }
#pragma unroll
            for (int k = 9; k < 16; ++k) { float d = es[k] - er[k]; i3 += d * d; }
            *(float4*)&feat_s[wave][lane][32] = make_float4(i0, i1, i2, i3);
        }
        // intra-wave LDS producer->consumer fence (no cross-wave sharing)
        asm volatile("s_waitcnt lgkmcnt(0)" ::: "memory");
        __builtin_amdgcn_sched_barrier(0);

        // ---- phase C: feat @ [WfInv | WfEv], cols (2*lane, 2*lane+1) ----
        float fwi0[16], fwi1[16], fwe0[16], fwe1[16];
#pragma unroll
        for (int b = 0; b < 16; ++b) {
            fwi0[b] = bi.x; fwi1[b] = bi.y; fwe0[b] = be.x; fwe1[b] = be.y;
        }
#pragma unroll
        for (int g = 0; g < 9; ++g) {
            const uint2 w0 = wcomb[(4 * g + 0) * 64 + lane];
            const uint2 w1 = wcomb[(4 * g + 1) * 64 + lane];
            const uint2 w2 = wcomb[(4 * g + 2) * 64 + lane];
            const uint2 w3 = wcomb[(4 * g + 3) * 64 + lane];
            const float wiA0 = bflo(w0.x), wiA1 = bfhi(w0.x), weA0 = bflo(w0.y), weA1 = bfhi(w0.y);
            const float wiB0 = bflo(w1.x), wiB1 = bfhi(w1.x), weB0 = bflo(w1.y), weB1 = bfhi(w1.y);
            const float wiC0 = bflo(w2.x), wiC1 = bfhi(w2.x), weC0 = bflo(w2.y), weC1 = bfhi(w2.y);
            const float wiD0 = bflo(w3.x), wiD1 = bfhi(w3.x), weD0 = bflo(w3.y), weD1 = bfhi(w3.y);
#pragma unroll
            for (int b = 0; b < 16; ++b) {
                const float4 f = *(const float4*)&feat_s[wave][b][4 * g];
                fwi0[b] += f.x * wiA0 + f.y * wiB0 + f.z * wiC0 + f.w * wiD0;
                fwi1[b] += f.x * wiA1 + f.y * wiB1 + f.z * wiC1 + f.w * wiD1;
                fwe0[b] += f.x * weA0 + f.y * weB0 + f.z * weC0 + f.w * weD0;
                fwe1[b] += f.x * weA1 + f.y * weB1 + f.z * weC1 + f.w * weD1;
            }
        }

        // ---- phase D: dots + scatter ----
#pragma unroll
        for (int b = 0; b < 16; ++b) {
            const int r = __builtin_amdgcn_readlane(rreg, b);
            const int s = __builtin_amdgcn_readlane(sreg, b);
            const float cut = __builtin_bit_cast(float,
                __builtin_amdgcn_readlane(__builtin_bit_cast(int, creg), b));
            const u32 qi = QIh[(size_t)r * 64 + lane];
            const u32 ki = KIh[(size_t)s * 64 + lane];
            const u32 vi = VIh[(size_t)s * 64 + lane];
            const u32 qe = QEh[(size_t)r * 64 + lane];
            const u32 ke = KEh[(size_t)s * 64 + lane];
            float pi = bflo(qi) * bflo(ki) * fwi0[b] + bfhi(qi) * bfhi(ki) * fwi1[b];
            float pe = bflo(qe) * bflo(ke) * fwe0[b] + bfhi(qe) * bfhi(ke) * fwe1[b];
            pi = red16(pi);                       // per-head sum (head = lane/16)
            pe = red16(pe);                       // per-degree sum (degree = lane/16)
            const float coef = cut * pi * rs32;
            float* dp = &dinv[(size_t)r * FF + 2 * lane];
            __hip_atomic_fetch_add(dp,     coef * bflo(vi),
                                   __ATOMIC_RELAXED, __HIP_MEMORY_SCOPE_AGENT);
            __hip_atomic_fetch_add(dp + 1, coef * bfhi(vi),
                                   __ATOMIC_RELAXED, __HIP_MEMORY_SCOPE_AGENT);
            // d_ev: degree row g handles its 2g+1 ev slots (offset g^2)
            const int g = lane >> 4, jj = lane & 15;
            if (jj < 2 * g + 1) {
                const int evo = g * g + jj;
                const float m = cut * pe * rs32 * sh[(size_t)(ebase + b) * 16 + evo];
                __hip_atomic_fetch_add(&devout[(size_t)r * 16 + evo], m,
                                       __ATOMIC_RELAXED, __HIP_MEMORY_SCOPE_AGENT);
            }
        }
    }
}

// ---------------------------------------------------------------------------
extern "C" void kernel_launch(void* const* d_in, const int* in_sizes, int n_in,
                              void* d_out, int out_size, void* d_ws,
                              size_t ws_size, hipStream_t stream) {
    const float* inv_features = (const float*)d_in[0];
    const float* ev_features  = (const float*)d_in[1];
    const float* rbf          = (const float*)d_in[2];
    const float* sh_vectors   = (const float*)d_in[3];
    const float* cutoffs      = (const float*)d_in[4];
    const float* W_q_inv      = (const float*)d_in[5];
    const float* W_k_inv      = (const float*)d_in[6];
    const float* W_v_inv      = (const float*)d_in[7];
    const float* W_q_ev       = (const float*)d_in[8];
    const float* W_k_ev       = (const float*)d_in[9];
    const float* Wf_inv       = (const float*)d_in[10];
    const float* bf_inv       = (const float*)d_in[11];
    const float* Wf_ev        = (const float*)d_in[12];
    const float* bf_ev        = (const float*)d_in[13];
    const int*   senders      = (const int*)d_in[14];
    const int*   receivers    = (const int*)d_in[15];

    u16* QI = (u16*)d_ws;                       // bf16 node arrays, 8 MB each
    u16* KI = QI + (size_t)NN * FF;
    u16* VI = KI + (size_t)NN * FF;
    u16* QE = VI + (size_t)NN * FF;
    u16* KE = QE + (size_t)NN * FF;

    float* dinv   = (float*)d_out;              // [N,128]
    float* devout = dinv + (size_t)NN * FF;     // [N,16]

    (void)hipMemsetAsync(d_out, 0, (size_t)out_size * sizeof(float), stream);

    node_kernel<<<1024, 256, 0, stream>>>(inv_features, W_q_inv, W_k_inv,
                                          W_v_inv, W_q_ev, W_k_ev,
                                          QI, KI, VI, QE, KE);

    edge_kernel<<<4096, 256, 0, stream>>>(ev_features, rbf, sh_vectors,
                                          cutoffs, Wf_inv, bf_inv, Wf_ev,
                                          bf_ev, senders, receivers,
                                          (const u32*)QI, (const u32*)KI,
                                          (const u32*)VI, (const u32*)QE,
                                          (const u32*)KE, dinv, devout);
}